// Round 3
// baseline (7096.297 us; speedup 1.0000x reference)
//
#include <hip/hip_runtime.h>
#include <math.h>

// LSTM: B=128, T=256, D=256, H=1024, C=10
// Round 3: persistent kernel (R2 design) with PLAIN launch — R2's cooperative
// launch never executed (d_out == stub-zero fingerprint); grid 256 blocks at
// 1 block/CU (VGPR-bound) == exact residency capacity, so the per-group
// 32-block spin barrier is deadlock-free without cooperative launch.
//   - group = blockIdx%8 owns 16 batch rows; member = blockIdx/8 owns 32
//     hidden units (x4 gates = 8 col-tiles of 16).
//   - Weights in REGISTERS: wave w holds 2 col-tiles x 40 k-tiles of MFMA
//     B-fragments (320 VGPRs/lane), loaded once from Wpack.
//   - Per step: stage A=[x_t|h] (16x1280) to LDS in A-frag order, 80 MFMAs
//     from registers, gate-exchange via LDS, cell update (c in registers),
//     write h slice, per-group arrival barrier (monotonic counter).
// Workspace layout (27,789,312 B used):
//   [0)          Wpack  bf16  10,485,760 B
//   [10485760)   xT     bf16  16,777,216 B   ([T][B][D])
//   [27262976)   h0     bf16     262,144 B
//   [27525120)   h1     bf16     262,144 B
//   [27787264)   counters 2,048 B (8 groups x 256 B)

#define BB 128
#define TT 256
#define DD 256
#define HH 1024
#define NKT 40   // 1280 / 32 k-tiles

typedef __bf16 bf16x8 __attribute__((ext_vector_type(8)));
typedef float  f32x4  __attribute__((ext_vector_type(4)));
typedef unsigned short u16;
typedef u16 u16x8 __attribute__((ext_vector_type(8)));

__device__ __forceinline__ u16 f2bf(float f){
  unsigned u = __builtin_bit_cast(unsigned, f);
  u += 0x7fffu + ((u >> 16) & 1u);            // round-to-nearest-even
  return (u16)(u >> 16);
}
__device__ __forceinline__ float bf2f(u16 b){
  unsigned u = ((unsigned)b) << 16;
  return __builtin_bit_cast(float, u);
}

// ---- pack weights into MFMA B-fragment order (verified R1) -----------------
__global__ void prep_wpack(const float* __restrict__ Wfx, const float* __restrict__ Wix,
                           const float* __restrict__ Wgx, const float* __restrict__ Wox,
                           const float* __restrict__ Wfh, const float* __restrict__ Wih,
                           const float* __restrict__ Wgh, const float* __restrict__ Woh,
                           u16* __restrict__ Wpack){
  int id = blockIdx.x * 256 + threadIdx.x;    // [0, 655360)
  int lane = id & 63;
  int kt = (id >> 6) % NKT;
  int ct = id / (64 * NKT);
  int col = ct * 16 + (lane & 15);
  int g = col >> 10, n = col & 1023;
  int kbase = kt * 32 + (lane >> 4) * 8;
  const float* Wx = (g==0) ? Wfx : (g==1) ? Wix : (g==2) ? Wgx : Wox;
  const float* Wh = (g==0) ? Wfh : (g==1) ? Wih : (g==2) ? Wgh : Woh;
  u16x8 v;
  #pragma unroll
  for (int j = 0; j < 8; ++j){
    int k = kbase + j;
    float f = (k < DD) ? Wx[k * HH + n] : Wh[(k - DD) * HH + n];
    v[j] = f2bf(f);
  }
  *(u16x8*)(Wpack + (size_t)id * 8) = v;
}

// ---- transpose+cast x: xT[t][b][d] = bf16(x[b][t][d]) (verified R1) --------
__global__ void prep_xT(const float* __restrict__ x, u16* __restrict__ xT){
  int id = blockIdx.x * 256 + threadIdx.x;    // [0, 1048576), 8 elems each
  int t = id >> 12;
  int b = (id >> 5) & 127;
  int d0 = (id & 31) * 8;
  const float* src = x + ((size_t)b * TT + t) * DD + d0;
  u16x8 v;
  #pragma unroll
  for (int j = 0; j < 8; ++j) v[j] = f2bf(src[j]);
  *(u16x8*)(xT + (size_t)id * 8) = v;
}

// ---- persistent LSTM over all 256 steps ------------------------------------
__global__ __launch_bounds__(256, 1) void lstm_persistent(
    const u16* __restrict__ xT, const u16* __restrict__ Wpack,
    u16* __restrict__ hb0, u16* __restrict__ hb1,
    unsigned* __restrict__ cnts,
    const float* __restrict__ bfv, const float* __restrict__ biv,
    const float* __restrict__ bgv, const float* __restrict__ bov){
  __shared__ u16x8 As4[NKT * 64];   // 40 KB, A tile in fragment order
  __shared__ float gLds[16][132];   // gate exchange

  const int tid = threadIdx.x;
  const int grp = blockIdx.x & 7;   // batch group (XCD-local under round-robin)
  const int mem = blockIdx.x >> 3;  // hidden-tile member [0,32)
  const int r0 = grp * 16;          // batch rows [r0, r0+16)
  const int n0 = mem * 32;          // hidden units [n0, n0+32)
  const int w = tid >> 6, lane = tid & 63, cr = lane & 15, q4 = lane >> 4;

  // ---- one-time: weights into registers (320 VGPRs/lane) ----
  bf16x8 w0[NKT], w1[NKT];
  {
    const size_t ct0 = (size_t)(w * 64 + mem * 2);
    const u16x8* wp = (const u16x8*)Wpack + ct0 * (NKT * 64) + lane;
    #pragma unroll
    for (int kt = 0; kt < NKT; ++kt){
      w0[kt] = __builtin_bit_cast(bf16x8, wp[kt * 64]);
      w1[kt] = __builtin_bit_cast(bf16x8, wp[NKT * 64 + kt * 64]);
    }
  }
  const float* bptr = (w==0) ? bfv : (w==1) ? biv : (w==2) ? bgv : bov;
  const float bias0 = bptr[n0 + cr], bias1 = bptr[n0 + 16 + cr];

  // cell-update ownership: thread -> (row, row+8) x unit nn
  const int urow = tid >> 5, unn = tid & 31;
  float creg0 = 0.f, creg1 = 0.f;   // c-state in registers
  unsigned* cnt = cnts + grp * 64;  // 256-B spaced per-group counter

  #pragma unroll 1
  for (int t = 0; t < TT; ++t){
    const u16* hcur = (t & 1) ? hb1 : hb0;
    u16*       hnxt = (t & 1) ? hb0 : hb1;
    const u16* xrow = xT + ((size_t)t * BB + r0) * DD;

    // ---- stage A into LDS (m-fast mapping: conflict-free b128 writes) ----
    #pragma unroll
    for (int it = 0; it < 10; ++it){
      int ch = tid + it * 256;          // [0, 2560)
      int m  = ch & 15;
      int k0 = (ch >> 4) * 8;
      const u16* src = (k0 < DD) ? (xrow + m * DD + k0)
                                 : (hcur + (r0 + m) * HH + (k0 - DD));
      u16x8 v = *(const u16x8*)src;
      int kt = k0 >> 5, q = (k0 >> 3) & 3;
      As4[kt * 64 + 16 * q + m] = v;
    }
    __syncthreads();

    // ---- K loop: 80 MFMAs from register weights, 4 acc chains ----
    f32x4 a0e = {0,0,0,0}, a0o = {0,0,0,0}, a1e = {0,0,0,0}, a1o = {0,0,0,0};
    #pragma unroll
    for (int kt = 0; kt < NKT; ++kt){
      bf16x8 a = __builtin_bit_cast(bf16x8, As4[kt * 64 + lane]);
      if (kt & 1){
        a0o = __builtin_amdgcn_mfma_f32_16x16x32_bf16(a, w0[kt], a0o, 0, 0, 0);
        a1o = __builtin_amdgcn_mfma_f32_16x16x32_bf16(a, w1[kt], a1o, 0, 0, 0);
      } else {
        a0e = __builtin_amdgcn_mfma_f32_16x16x32_bf16(a, w0[kt], a0e, 0, 0, 0);
        a1e = __builtin_amdgcn_mfma_f32_16x16x32_bf16(a, w1[kt], a1e, 0, 0, 0);
      }
    }
    f32x4 acc0 = a0e + a0o, acc1 = a1e + a1o;

    // ---- gate exchange (C/D layout: col=lane&15, row=q4*4+r) ----
    #pragma unroll
    for (int r = 0; r < 4; ++r){
      gLds[q4 * 4 + r][w * 32 + cr]      = acc0[r] + bias0;
      gLds[q4 * 4 + r][w * 32 + 16 + cr] = acc1[r] + bias1;
    }
    __syncthreads();

    // ---- cell update: 2 (row,unit) pairs per thread, c in registers ----
    {
      float fp = gLds[urow][unn],      ip = gLds[urow][32 + unn];
      float gp = gLds[urow][64 + unn], op = gLds[urow][96 + unn];
      float fs = 1.f / (1.f + expf(-fp));
      float is = 1.f / (1.f + expf(-ip));
      float gs = tanhf(gp);
      float os = 1.f / (1.f + expf(-op));
      creg0 = gs * is + creg0 * fs;
      hnxt[(r0 + urow) * HH + n0 + unn] = f2bf(tanhf(creg0) * os);
    }
    {
      int row = urow + 8;
      float fp = gLds[row][unn],      ip = gLds[row][32 + unn];
      float gp = gLds[row][64 + unn], op = gLds[row][96 + unn];
      float fs = 1.f / (1.f + expf(-fp));
      float is = 1.f / (1.f + expf(-ip));
      float gs = tanhf(gp);
      float os = 1.f / (1.f + expf(-op));
      creg1 = gs * is + creg1 * fs;
      hnxt[(r0 + row) * HH + n0 + unn] = f2bf(tanhf(creg1) * os);
    }

    // ---- per-group barrier (32 blocks): release h_t, acquire for t+1 ----
    __threadfence();          // make this thread's h stores agent-visible
    __syncthreads();
    if (tid == 0){
      __hip_atomic_fetch_add(cnt, 1u, __ATOMIC_RELEASE, __HIP_MEMORY_SCOPE_AGENT);
      unsigned tgt = 32u * (unsigned)(t + 1);
      while (__hip_atomic_load(cnt, __ATOMIC_RELAXED, __HIP_MEMORY_SCOPE_AGENT) < tgt){
        __builtin_amdgcn_s_sleep(1);
      }
      __threadfence();        // acquire: invalidate caches before reading h_t
    }
    __syncthreads();
  }
}

// ---- out[b][c] = h_T[b] . Wph[:,c] + bp[c] (verified R1) -------------------
__global__ void final_proj(const u16* __restrict__ h, const float* __restrict__ Wph,
                           const float* __restrict__ bp, float* __restrict__ out){
  __shared__ float red[10][256];
  int b = blockIdx.x, tid = threadIdx.x;
  float p[10];
  #pragma unroll
  for (int c = 0; c < 10; ++c) p[c] = 0.f;
  for (int k = tid; k < HH; k += 256){
    float hv = bf2f(h[b * HH + k]);
    const float* wr = Wph + (size_t)k * 10;
    #pragma unroll
    for (int c = 0; c < 10; ++c) p[c] += hv * wr[c];
  }
  #pragma unroll
  for (int c = 0; c < 10; ++c) red[c][tid] = p[c];
  __syncthreads();
  for (int s = 128; s > 0; s >>= 1){
    if (tid < s){
      #pragma unroll
      for (int c = 0; c < 10; ++c) red[c][tid] += red[c][tid + s];
    }
    __syncthreads();
  }
  if (tid < 10) out[b * 10 + tid] = red[tid][0] + bp[tid];
}

extern "C" void kernel_launch(void* const* d_in, const int* in_sizes, int n_in,
                              void* d_out, int out_size, void* d_ws, size_t ws_size,
                              hipStream_t stream){
  (void)in_sizes; (void)n_in; (void)out_size; (void)ws_size;
  const float* x   = (const float*)d_in[0];
  const float* Wfx = (const float*)d_in[1];
  const float* Wix = (const float*)d_in[2];
  const float* Wgx = (const float*)d_in[3];
  const float* Wox = (const float*)d_in[4];
  const float* Wfh = (const float*)d_in[5];
  const float* Wih = (const float*)d_in[6];
  const float* Wgh = (const float*)d_in[7];
  const float* Woh = (const float*)d_in[8];
  const float* bfv = (const float*)d_in[9];
  const float* biv = (const float*)d_in[10];
  const float* bgv = (const float*)d_in[11];
  const float* bov = (const float*)d_in[12];
  const float* Wph = (const float*)d_in[13];
  const float* bp  = (const float*)d_in[14];

  char* ws = (char*)d_ws;
  u16*  Wpack = (u16*)ws;                    // 10,485,760 B
  u16*  xT    = (u16*)(ws + 10485760);       // 16,777,216 B
  u16*  h0    = (u16*)(ws + 27262976);       //    262,144 B
  u16*  h1    = (u16*)(ws + 27525120);       //    262,144 B
  unsigned* cnts = (unsigned*)(ws + 27787264); //   2,048 B

  prep_wpack<<<2560, 256, 0, stream>>>(Wfx, Wix, Wgx, Wox, Wfh, Wih, Wgh, Woh, Wpack);
  prep_xT<<<4096, 256, 0, stream>>>(x, xT);
  hipMemsetAsync(h0, 0, 262144, stream);
  hipMemsetAsync(cnts, 0, 2048, stream);

  // Plain launch: grid == residency capacity (256 blocks, 1/CU) so the
  // per-group spin barrier cannot deadlock; cooperative launch failed under
  // the harness's capture path in R2.
  lstm_persistent<<<dim3(256), dim3(256), 0, stream>>>(
      xT, Wpack, h0, h1, cnts, bfv, biv, bgv, bov);

  // t=255 (odd) wrote h0 -> final hidden state lives in h0
  final_proj<<<128, 256, 0, stream>>>(h0, Wph, bp, (float*)d_out);
}